// Round 1
// baseline (183.297 us; speedup 1.0000x reference)
//
#include <hip/hip_runtime.h>
#include <cmath>

// SSIM loss, fused separable implementation.
// X, Y: (16, 4, 512, 512) fp32.  Window 11x11 Gaussian (sigma=1.5), VALID conv
// -> 502x502 maps; ssim_map -> scalar 1 - mean.

#define WS      11
#define RAD     5
#define OT      32              // output tile (square)
#define IT      (OT + WS - 1)   // 42 input tile
#define IMG     512
#define ODIM    (IMG - WS + 1)  // 502
#define TILES   16              // ceil(502/32)
#define NC      64              // 16 batch * 4 channels
#define NBLOCKS (TILES * TILES * NC)

struct GaussW { float g[WS]; };

__global__ __launch_bounds__(256) void ssim_tile_kernel(
    const float* __restrict__ X, const float* __restrict__ Y,
    float* __restrict__ partial, GaussW gw)
{
    __shared__ float sX[IT][IT];
    __shared__ float sY[IT][IT];
    // horizontal pass results: muX, muY, E[XX], E[YY], E[XY]
    __shared__ float hq[5][IT][OT];

    const int tid = threadIdx.x;
    const int ox0 = blockIdx.x * OT;
    const int oy0 = blockIdx.y * OT;
    const int nc  = blockIdx.z;

    const float* Xp = X + (size_t)nc * IMG * IMG;
    const float* Yp = Y + (size_t)nc * IMG * IMG;

    // ---- stage raw 42x42 tiles into LDS ----
    for (int i = tid; i < IT * IT; i += 256) {
        const int iy = i / IT, ix = i - iy * IT;
        const int gy = oy0 + iy, gx = ox0 + ix;
        float xv = 0.f, yv = 0.f;
        if (gy < IMG && gx < IMG) {
            const size_t off = (size_t)gy * IMG + gx;
            xv = Xp[off];
            yv = Yp[off];
        }
        sX[iy][ix] = xv;
        sY[iy][ix] = yv;
    }
    __syncthreads();

    // ---- horizontal 11-tap pass: 42 rows x 32 cols ----
    for (int i = tid; i < IT * OT; i += 256) {
        const int iy = i / OT, ox = i - iy * OT;
        float aM = 0.f, aN = 0.f, aXX = 0.f, aYY = 0.f, aXY = 0.f;
#pragma unroll
        for (int k = 0; k < WS; ++k) {
            const float w = gw.g[k];
            const float x = sX[iy][ox + k];
            const float y = sY[iy][ox + k];
            aM  = fmaf(w, x,     aM);
            aN  = fmaf(w, y,     aN);
            aXX = fmaf(w, x * x, aXX);
            aYY = fmaf(w, y * y, aYY);
            aXY = fmaf(w, x * y, aXY);
        }
        hq[0][iy][ox] = aM;
        hq[1][iy][ox] = aN;
        hq[2][iy][ox] = aXX;
        hq[3][iy][ox] = aYY;
        hq[4][iy][ox] = aXY;
    }
    __syncthreads();

    // ---- vertical 11-tap pass + SSIM map + local accumulate ----
    float acc = 0.f;
    for (int i = tid; i < OT * OT; i += 256) {
        const int oy = i / OT, ox = i - oy * OT;
        const int gy = oy0 + oy, gx = ox0 + ox;
        if (gy < ODIM && gx < ODIM) {
            float mX = 0.f, mY = 0.f, eXX = 0.f, eYY = 0.f, eXY = 0.f;
#pragma unroll
            for (int k = 0; k < WS; ++k) {
                const float w = gw.g[k];
                mX  = fmaf(w, hq[0][oy + k][ox], mX);
                mY  = fmaf(w, hq[1][oy + k][ox], mY);
                eXX = fmaf(w, hq[2][oy + k][ox], eXX);
                eYY = fmaf(w, hq[3][oy + k][ox], eYY);
                eXY = fmaf(w, hq[4][oy + k][ox], eXY);
            }
            const float muXX = mX * mX;
            const float muYY = mY * mY;
            const float muXY = mX * mY;
            const float sXX = eXX - muXX;
            const float sYY = eYY - muYY;
            const float sXY = eXY - muXY;
            const float C1 = 1e-4f, C2 = 9e-4f;
            const float num = (2.f * muXY + C1) * (2.f * sXY + C2);
            const float den = (muXX + muYY + C1) * (sXX + sYY + C2);
            acc += num / den;
        }
    }

    // ---- deterministic block reduction ----
#pragma unroll
    for (int off = 32; off > 0; off >>= 1)
        acc += __shfl_down(acc, off, 64);

    __shared__ float wsum[4];
    const int wave = tid >> 6, lane = tid & 63;
    if (lane == 0) wsum[wave] = acc;
    __syncthreads();
    if (tid == 0) {
        const float t = (wsum[0] + wsum[1]) + (wsum[2] + wsum[3]);
        partial[((size_t)blockIdx.z * gridDim.y + blockIdx.y) * gridDim.x + blockIdx.x] = t;
    }
}

__global__ __launch_bounds__(256) void ssim_finish_kernel(
    const float* __restrict__ partial, float* __restrict__ out, int n)
{
    __shared__ double sd[256];
    double local = 0.0;
    for (int i = threadIdx.x; i < n; i += 256)
        local += (double)partial[i];
    sd[threadIdx.x] = local;
    __syncthreads();
    for (int s = 128; s > 0; s >>= 1) {
        if (threadIdx.x < s) sd[threadIdx.x] += sd[threadIdx.x + s];
        __syncthreads();
    }
    if (threadIdx.x == 0) {
        const double cnt = (double)NC * (double)ODIM * (double)ODIM;
        out[0] = (float)(1.0 - sd[0] / cnt);
    }
}

extern "C" void kernel_launch(void* const* d_in, const int* in_sizes, int n_in,
                              void* d_out, int out_size, void* d_ws, size_t ws_size,
                              hipStream_t stream) {
    const float* X = (const float*)d_in[0];
    const float* Y = (const float*)d_in[1];
    float* out = (float*)d_out;
    float* partial = (float*)d_ws;   // NBLOCKS floats = 64 KiB

    // Gaussian taps: computed in float64 then rounded to f32 (matches numpy).
    GaussW gw;
    {
        double gd[WS], s = 0.0;
        for (int i = 0; i < WS; ++i) {
            const double x = (double)(i - RAD);
            gd[i] = std::exp(-(x * x) / (2.0 * 1.5 * 1.5));
            s += gd[i];
        }
        for (int i = 0; i < WS; ++i) gw.g[i] = (float)(gd[i] / s);
    }

    dim3 grid(TILES, TILES, NC);
    ssim_tile_kernel<<<grid, 256, 0, stream>>>(X, Y, partial, gw);
    ssim_finish_kernel<<<1, 256, 0, stream>>>(partial, out, NBLOCKS);
}